// Round 17
// baseline (1921.553 us; speedup 1.0000x reference)
//
#include <hip/hip_runtime.h>

typedef __bf16 bf16x8 __attribute__((ext_vector_type(8)));
typedef float f32x4 __attribute__((ext_vector_type(4)));
typedef unsigned int u32x4 __attribute__((ext_vector_type(4)));

union UQ { uint4 q; u32x4 p; bf16x8 v; __bf16 b[8]; unsigned long long d[2]; };

__device__ __forceinline__ unsigned short f2bf(float x){
  union { float f; unsigned u; } c; c.f = x;
  return (unsigned short)((c.u + 0x7fffu + ((c.u >> 16) & 1u)) >> 16);
}

__global__ void zero_flags(int* __restrict__ p){
  p[threadIdx.x] = 0;
}

// Pack W (512x512 f32 row-major) into canonical MFMA fragment stream:
// dst[(ntile*16 + kt)*64 + lane] = 8 bf16 of W[ntile*16 + (lane&15)][kt*32 + (lane>>4)*8 + j]
__global__ void pack_kernel(const float* __restrict__ W, uint4* __restrict__ dst){
  int tid  = blockIdx.x * 512 + threadIdx.x;   // 0..32767
  int lane = tid & 63;
  int kt   = (tid >> 6) & 15;
  int ntl  = tid >> 10;
  int row  = ntl * 16 + (lane & 15);
  int k0   = kt * 32 + ((lane >> 4) << 3);
  const float* s = &W[row * 512 + k0];
  unsigned a0 = f2bf(s[0]) | ((unsigned)f2bf(s[1]) << 16);
  unsigned a1 = f2bf(s[2]) | ((unsigned)f2bf(s[3]) << 16);
  unsigned a2 = f2bf(s[4]) | ((unsigned)f2bf(s[5]) << 16);
  unsigned a3 = f2bf(s[6]) | ((unsigned)f2bf(s[7]) << 16);
  dst[tid] = (uint4){a0, a1, a2, a3};
}

// h0[b][n] = sum_o init[b][o] * Whi[n][o]; also bf16 copy for step-0 staging
__global__ void h0_kernel(const float* __restrict__ init, const float* __restrict__ Whi,
                          float* __restrict__ h0, unsigned short* __restrict__ hb0){
  int b = blockIdx.x, n = threadIdx.x;  // 256 x 512
  __shared__ float ic[512];
  ic[n] = init[b * 512 + n];
  __syncthreads();
  const float4* wr = (const float4*)&Whi[n * 512];
  float s = 0.f;
  #pragma unroll 8
  for (int o = 0; o < 128; o++){
    float4 w = wr[o];
    s += w.x * ic[4*o] + w.y * ic[4*o+1] + w.z * ic[4*o+2] + w.w * ic[4*o+3];
  }
  h0[b * 512 + n] = s;
  hb0[b * 512 + n] = f2bf(s);
}

// Fused kernel: WGs 0..15 = r10 "fortress" rnn + per-64-step progress publish.
// WGs 16..2063 = out_gemm 64-row-tile consumers, t-chunk-major order.
// r17 deltas vs r16: (a) conflict-free staging swizzle (slot ^= (r&7)^block),
// (b) s_sleep backoff in spin, (c) rnn aug-MFMA moved after kt15 (hides xv load).
__global__ __launch_bounds__(512, 1)
void rnn_gemm(const float* __restrict__ inputs, const float* __restrict__ W_in,
              const float* __restrict__ b_in, const float* __restrict__ b_rec,
              const uint4* __restrict__ wfrag, const uint4* __restrict__ wofrag,
              const float* __restrict__ h0, const unsigned short* __restrict__ hb0,
              int* __restrict__ progress, float* __restrict__ hidden,
              float* __restrict__ outp){
  __shared__ char smem[147456];
  const int bid = blockIdx.x;
  const int tid = threadIdx.x, w = tid >> 6, lane = tid & 63;
  const int col = lane & 15, quad = lane >> 4;

  if (bid < 16){
    // ================= RNN role =================
    const int m = bid;
    const int g16 = m << 4;
    const int nbase = w << 6;
    const int swc = (col & 7) << 3;
    unsigned short* hbuf = (unsigned short*)smem;          // 16 KB
    uint4* wlds = (uint4*)(smem + 16384);                  // 128 KB

    UQ u[32];
    #pragma unroll
    for (int kt = 0; kt < 8; kt++)
      #pragma unroll
      for (int nt = 0; nt < 4; nt++){
        const uint4* src = &wfrag[(((w << 2) + nt) * 16 + kt) * 64 + lane];
        asm volatile("global_load_dwordx4 %0, %1, off"
                     : "=v"(u[kt * 4 + nt].p) : "v"(src) : "memory");
      }
    asm volatile("s_waitcnt vmcnt(0)" ::: "memory");
    #pragma unroll
    for (int j = 0; j < 32; j++)
      asm volatile("" : "+v"(u[j].d[0]), "+v"(u[j].d[1]));

    #pragma unroll
    for (int kt = 8; kt < 12; kt++)
      #pragma unroll
      for (int nt = 0; nt < 4; nt++)
        wlds[(w * 16 + (kt - 8) * 4 + nt) * 64 + lane] =
            wfrag[(((w << 2) + nt) * 16 + kt) * 64 + lane];

    UQ uaug[4];
    #pragma unroll
    for (int nt = 0; nt < 4; nt++){
      uaug[nt].d[0] = 0; uaug[nt].d[1] = 0;
      if (quad == 0){
        int n = nbase + nt * 16 + col;
        uaug[nt].b[0] = (__bf16)W_in[2 * n];
        uaug[nt].b[1] = (__bf16)W_in[2 * n + 1];
        uaug[nt].b[2] = (__bf16)(b_in[n] + b_rec[n]);
      }
    }

    float h[16];
    #pragma unroll
    for (int nt = 0; nt < 4; nt++){
      float4 h4 = *(const float4*)&h0[(g16 + col) * 512 + nbase + nt * 16 + (quad << 2)];
      h[nt*4+0] = h4.x; h[nt*4+1] = h4.y; h[nt*4+2] = h4.z; h[nt*4+3] = h4.w;
    }

    {
      int b = tid >> 5, n0 = (tid & 31) << 4;
      const uint4* s4 = (const uint4*)&hb0[(g16 + b) * 512 + n0];
      uint4 v0 = s4[0], v1 = s4[1];
      int sw = (b & 7) << 3;
      *(uint4*)&hbuf[(b << 9) + (n0 ^ sw)]       = v0;
      *(uint4*)&hbuf[(b << 9) + ((n0 + 8) ^ sw)] = v1;
    }
    __syncthreads();

    unsigned long long wsp = (unsigned long long)wfrag;
    const float2* xsrc = (const float2*)&inputs[((size_t)(g16 + col)) << 10];

#define ISSUE(b1) { const int kt_ = 12 + (b1);                                    \
    _Pragma("unroll")                                                             \
    for (int nt_ = 0; nt_ < 4; nt_++)                                             \
      sv[(b1)*4 + nt_].q = ws[(((w << 2) + nt_) * 16 + kt_) * 64 + lane]; }

#define HREAD(kt_) *(const uint4*)&hbuf[(col << 9) + ((((kt_) << 5) + (quad << 3)) ^ swc)]

    for (int t = 0; t < 512; t++){
      asm volatile("" : "+s"(wsp));
      const uint4* ws = (const uint4*)wsp;

      // issue xv load early; its consumer (aug-MFMA) now runs LAST in the step
      float2 xv = xsrc[t];

      f32x4 acc[4];
      #pragma unroll
      for (int nt = 0; nt < 4; nt++) acc[nt] = (f32x4){0.f, 0.f, 0.f, 0.f};

      UQ sv[16];
      ISSUE(0);
      UQ bh[16];
      #pragma unroll
      for (int kt = 0; kt < 16; kt++)
        bh[kt].q = HREAD(kt);

      #pragma unroll
      for (int kt = 0; kt < 8; kt++){
        #pragma unroll
        for (int nt = 0; nt < 4; nt++)
          acc[nt] = __builtin_amdgcn_mfma_f32_16x16x32_bf16(u[kt*4+nt].v, bh[kt].v, acc[nt], 0, 0, 0);
        if (kt == 0) ISSUE(1);
        if (kt == 2) ISSUE(2);
        if (kt == 4) ISSUE(3);
      }
      #pragma unroll
      for (int kt = 8; kt < 12; kt++){
        #pragma unroll
        for (int nt = 0; nt < 4; nt++){
          UQ a; a.q = wlds[(w * 16 + (kt - 8) * 4 + nt) * 64 + lane];
          acc[nt] = __builtin_amdgcn_mfma_f32_16x16x32_bf16(a.v, bh[kt].v, acc[nt], 0, 0, 0);
        }
      }
      #pragma unroll
      for (int kt = 12; kt < 16; kt++){
        #pragma unroll
        for (int nt = 0; nt < 4; nt++)
          acc[nt] = __builtin_amdgcn_mfma_f32_16x16x32_bf16(sv[(kt-12)*4+nt].v, bh[kt].v, acc[nt], 0, 0, 0);
      }

      // aug K-tile last: xv latency hidden under the 16-kt chain above
      {
        UQ baug; baug.d[0] = 0; baug.d[1] = 0;
        if (quad == 0){
          baug.b[0] = (__bf16)xv.x; baug.b[1] = (__bf16)xv.y; baug.b[2] = (__bf16)1.0f;
        }
        #pragma unroll
        for (int nt = 0; nt < 4; nt++)
          acc[nt] = __builtin_amdgcn_mfma_f32_16x16x32_bf16(uaug[nt].v, baug.v, acc[nt], 0, 0, 0);
      }

      __syncthreads();   // barrier A

      #pragma unroll
      for (int nt = 0; nt < 4; nt++){
        UQ hw; hw.d[0] = 0; hw.d[1] = 0;
        #pragma unroll
        for (int r = 0; r < 4; r++){
          float z  = acc[nt][r];
          float e  = __expf(2.0f * z);
          float rc = __builtin_amdgcn_rcpf(e + 1.0f);
          float hn = fmaf(0.9f, h[nt*4+r], 0.1f) - 0.2f * rc;
          h[nt*4+r] = hn;
          hw.b[r] = (__bf16)hn;
        }
        *(unsigned long long*)&hbuf[(col << 9) + ((nbase + (nt << 4) + (quad << 2)) ^ swc)] = hw.d[0];
        *(float4*)&hidden[((size_t)(g16 + col) * 512 + t) * 512 + nbase + (nt << 4) + (quad << 2)] =
            (float4){h[nt*4+0], h[nt*4+1], h[nt*4+2], h[nt*4+3]};
      }
      __syncthreads();   // barrier B

      if (((t + 1) & 63) == 0){
        asm volatile("s_waitcnt vmcnt(0)" ::: "memory");
        __syncthreads();
        if (tid == 0){
          __builtin_amdgcn_fence(__ATOMIC_RELEASE, "agent");
          __hip_atomic_store(&progress[m], t + 1, __ATOMIC_RELAXED, __HIP_MEMORY_SCOPE_AGENT);
        }
      }
    }
#undef ISSUE
#undef HREAD
  } else {
    // ========== GEMM role: 64-row tiles, t-chunk-major, upfront staging ======
    const int gid = bid - 16;                 // 0..2047
    const int tchunk = gid >> 8;              // 0..7  (dispatch order == time)
    const int b   = gid & 255;                // batch
    const int t0  = tchunk << 6;
    const int m0  = (b << 9) + t0;            // row base (64 rows)
    const int grp = b >> 4;
    const int ms  = w >> 1;                   // 0..3: 16-row slice
    const int nh  = w & 1;                    // 0..1: 256-col half
    unsigned short* albf = (unsigned short*)smem;      // 64 KB A-tile (64x512 bf16)
    uint4* wq = (uint4*)(smem + 65536);                // 32 KB W-frags per kt

    if (tid == 0)
      while (__hip_atomic_load(&progress[grp], __ATOMIC_RELAXED,
                               __HIP_MEMORY_SCOPE_AGENT) < t0 + 64)
        __builtin_amdgcn_s_sleep(8);          // backoff: don't hammer the LLC line
    __syncthreads();

    // ---- stage full 64x512 A-tile: 32 pipelined atomic ULL loads per thread
    // swizzle: 16B-slot ^= (r&7) ^ block(byte>>7) — conflict-free writes,
    // 2-way (free) reads.
    {
      const int r  = tid >> 3;                // 0..63
      const int c0 = (tid & 7) << 6;          // halfword col base, 0..448
      const unsigned long long* hp =
          (const unsigned long long*)&hidden[(size_t)(m0 + r) * 512 + c0];
      unsigned long long dv[32];
      #pragma unroll
      for (int j = 0; j < 32; j++)
        dv[j] = __hip_atomic_load(hp + j, __ATOMIC_RELAXED, __HIP_MEMORY_SCOPE_AGENT);
      const int sw = (((r & 7) ^ (c0 >> 6)) << 4);   // byte swizzle (bits 4-6)
      #pragma unroll
      for (int g = 0; g < 8; g++){            // 8 halfwords per group -> uint4
        union { unsigned long long d[4]; float f[8]; } cv;
        cv.d[0] = dv[g*4]; cv.d[1] = dv[g*4+1]; cv.d[2] = dv[g*4+2]; cv.d[3] = dv[g*4+3];
        uint4 o;
        o.x = f2bf(cv.f[0]) | ((unsigned)f2bf(cv.f[1]) << 16);
        o.y = f2bf(cv.f[2]) | ((unsigned)f2bf(cv.f[3]) << 16);
        o.z = f2bf(cv.f[4]) | ((unsigned)f2bf(cv.f[5]) << 16);
        o.w = f2bf(cv.f[6]) | ((unsigned)f2bf(cv.f[7]) << 16);
        int byteoff = (r << 10) + ((((c0 + (g << 3)) << 1)) ^ sw);
        *(uint4*)((char*)albf + byteoff) = o;
      }
    }
    __syncthreads();

    f32x4 acc[16];
    #pragma unroll
    for (int nt = 0; nt < 16; nt++) acc[nt] = (f32x4){0.f, 0.f, 0.f, 0.f};

    for (int kt = 0; kt < 16; kt++){
      // stage W-frags for this kt: 32 frags x 64 lanes, 4 per thread
      #pragma unroll
      for (int j = 0; j < 4; j++){
        int idx = (j << 9) + tid;             // 0..2047
        wq[(idx >> 6) * 64 + (idx & 63)] = wofrag[(((idx >> 6) << 4) + kt) * 64 + (idx & 63)];
      }
      __syncthreads();

      bf16x8 af;
      {
        int rl = (ms << 4) + col;
        int byteoff = (rl << 10)
                    + (((kt << 6) + (quad << 4)) ^ ((((rl & 7) ^ (kt >> 1)) << 4)));
        af = *(const bf16x8*)((const char*)albf + byteoff);
      }

      #pragma unroll
      for (int nt = 0; nt < 16; nt++){
        UQ uu; uu.q = wq[((nh << 4) + nt) * 64 + lane];
        acc[nt] = __builtin_amdgcn_mfma_f32_16x16x32_bf16(af, uu.v, acc[nt], 0, 0, 0);
      }
      __syncthreads();
    }

    #pragma unroll
    for (int nt = 0; nt < 16; nt++)
      #pragma unroll
      for (int r = 0; r < 4; r++)
        outp[(size_t)(m0 + (ms << 4) + (quad << 2) + r) * 512
             + (nh << 8) + (nt << 4) + col] = acc[nt][r];
  }
}

extern "C" void kernel_launch(void* const* d_in, const int* in_sizes, int n_in,
                              void* d_out, int out_size, void* d_ws, size_t ws_size,
                              hipStream_t stream){
  const float* inputs  = (const float*)d_in[0];  // (256,512,2)
  const float* initc   = (const float*)d_in[1];  // (256,512)
  const float* W_in    = (const float*)d_in[2];  // (512,2)
  const float* b_in    = (const float*)d_in[3];  // (512)
  const float* W_rec   = (const float*)d_in[4];  // (512,512)
  const float* b_rec   = (const float*)d_in[5];  // (512)
  const float* W_out   = (const float*)d_in[6];  // (512,512)
  const float* W_hi    = (const float*)d_in[7];  // (512,512)

  float* hidden  = (float*)d_out;                 // 256*512*512
  float* outputs = hidden + (size_t)67108864;     // second half

  char* ws = (char*)d_ws;
  uint4*          wrec_f  = (uint4*)ws;                           // 512 KB
  uint4*          wout_f  = (uint4*)(ws + (512 << 10));           // 512 KB
  float*          h0      = (float*)(ws + (1024 << 10));          // 512 KB
  unsigned short* hb0     = (unsigned short*)(ws + (1536 << 10)); // 256 KB
  int*            progress= (int*)(ws + (1792 << 10));            // 64 B

  zero_flags<<<1, 64, 0, stream>>>(progress);
  pack_kernel<<<64, 512, 0, stream>>>(W_rec, wrec_f);
  pack_kernel<<<64, 512, 0, stream>>>(W_out, wout_f);
  h0_kernel<<<256, 512, 0, stream>>>(initc, W_hi, h0, hb0);
  rnn_gemm<<<2064, 512, 0, stream>>>(inputs, W_in, b_in, b_rec, wrec_f, wout_f,
                                     h0, hb0, progress, hidden, outputs);
}

// Round 18
// 1721.444 us; speedup vs baseline: 1.1162x; 1.1162x over previous
//
#include <hip/hip_runtime.h>

typedef __bf16 bf16x8 __attribute__((ext_vector_type(8)));
typedef float f32x4 __attribute__((ext_vector_type(4)));
typedef unsigned int u32x4 __attribute__((ext_vector_type(4)));

union UQ { uint4 q; u32x4 p; bf16x8 v; __bf16 b[8]; unsigned long long d[2]; };

__device__ __forceinline__ unsigned short f2bf(float x){
  union { float f; unsigned u; } c; c.f = x;
  return (unsigned short)((c.u + 0x7fffu + ((c.u >> 16) & 1u)) >> 16);
}

__global__ void zero_flags(int* __restrict__ p){
  p[threadIdx.x] = 0;
}

// Pack W (512x512 f32 row-major) into canonical MFMA fragment stream:
// dst[(ntile*16 + kt)*64 + lane] = 8 bf16 of W[ntile*16 + (lane&15)][kt*32 + (lane>>4)*8 + j]
__global__ void pack_kernel(const float* __restrict__ W, uint4* __restrict__ dst){
  int tid  = blockIdx.x * 512 + threadIdx.x;   // 0..32767
  int lane = tid & 63;
  int kt   = (tid >> 6) & 15;
  int ntl  = tid >> 10;
  int row  = ntl * 16 + (lane & 15);
  int k0   = kt * 32 + ((lane >> 4) << 3);
  const float* s = &W[row * 512 + k0];
  unsigned a0 = f2bf(s[0]) | ((unsigned)f2bf(s[1]) << 16);
  unsigned a1 = f2bf(s[2]) | ((unsigned)f2bf(s[3]) << 16);
  unsigned a2 = f2bf(s[4]) | ((unsigned)f2bf(s[5]) << 16);
  unsigned a3 = f2bf(s[6]) | ((unsigned)f2bf(s[7]) << 16);
  dst[tid] = (uint4){a0, a1, a2, a3};
}

// h0[b][n] = sum_o init[b][o] * Whi[n][o]; also bf16 copy for step-0 staging
__global__ void h0_kernel(const float* __restrict__ init, const float* __restrict__ Whi,
                          float* __restrict__ h0, unsigned short* __restrict__ hb0){
  int b = blockIdx.x, n = threadIdx.x;  // 256 x 512
  __shared__ float ic[512];
  ic[n] = init[b * 512 + n];
  __syncthreads();
  const float4* wr = (const float4*)&Whi[n * 512];
  float s = 0.f;
  #pragma unroll 8
  for (int o = 0; o < 128; o++){
    float4 w = wr[o];
    s += w.x * ic[4*o] + w.y * ic[4*o+1] + w.z * ic[4*o+2] + w.w * ic[4*o+3];
  }
  h0[b * 512 + n] = s;
  hb0[b * 512 + n] = f2bf(s);
}

// Fused kernel: WGs 0..15 = r10 "fortress" rnn + per-64-step progress publish.
// WGs 16..2063 = out_gemm 64-row-tile consumers, t-chunk-major order.
// r18 = r16 exactly + conflict-free staging swizzle ONLY (r17 isolated the
// swizzle as good, aug-move and s_sleep as bad).
__global__ __launch_bounds__(512, 1)
void rnn_gemm(const float* __restrict__ inputs, const float* __restrict__ W_in,
              const float* __restrict__ b_in, const float* __restrict__ b_rec,
              const uint4* __restrict__ wfrag, const uint4* __restrict__ wofrag,
              const float* __restrict__ h0, const unsigned short* __restrict__ hb0,
              int* __restrict__ progress, float* __restrict__ hidden,
              float* __restrict__ outp){
  __shared__ char smem[147456];
  const int bid = blockIdx.x;
  const int tid = threadIdx.x, w = tid >> 6, lane = tid & 63;
  const int col = lane & 15, quad = lane >> 4;

  if (bid < 16){
    // ================= RNN role (r16 verbatim) =================
    const int m = bid;
    const int g16 = m << 4;
    const int nbase = w << 6;
    const int swc = (col & 7) << 3;
    unsigned short* hbuf = (unsigned short*)smem;          // 16 KB
    uint4* wlds = (uint4*)(smem + 16384);                  // 128 KB

    UQ u[32];
    #pragma unroll
    for (int kt = 0; kt < 8; kt++)
      #pragma unroll
      for (int nt = 0; nt < 4; nt++){
        const uint4* src = &wfrag[(((w << 2) + nt) * 16 + kt) * 64 + lane];
        asm volatile("global_load_dwordx4 %0, %1, off"
                     : "=v"(u[kt * 4 + nt].p) : "v"(src) : "memory");
      }
    asm volatile("s_waitcnt vmcnt(0)" ::: "memory");
    #pragma unroll
    for (int j = 0; j < 32; j++)
      asm volatile("" : "+v"(u[j].d[0]), "+v"(u[j].d[1]));

    #pragma unroll
    for (int kt = 8; kt < 12; kt++)
      #pragma unroll
      for (int nt = 0; nt < 4; nt++)
        wlds[(w * 16 + (kt - 8) * 4 + nt) * 64 + lane] =
            wfrag[(((w << 2) + nt) * 16 + kt) * 64 + lane];

    UQ uaug[4];
    #pragma unroll
    for (int nt = 0; nt < 4; nt++){
      uaug[nt].d[0] = 0; uaug[nt].d[1] = 0;
      if (quad == 0){
        int n = nbase + nt * 16 + col;
        uaug[nt].b[0] = (__bf16)W_in[2 * n];
        uaug[nt].b[1] = (__bf16)W_in[2 * n + 1];
        uaug[nt].b[2] = (__bf16)(b_in[n] + b_rec[n]);
      }
    }

    float h[16];
    #pragma unroll
    for (int nt = 0; nt < 4; nt++){
      float4 h4 = *(const float4*)&h0[(g16 + col) * 512 + nbase + nt * 16 + (quad << 2)];
      h[nt*4+0] = h4.x; h[nt*4+1] = h4.y; h[nt*4+2] = h4.z; h[nt*4+3] = h4.w;
    }

    {
      int b = tid >> 5, n0 = (tid & 31) << 4;
      const uint4* s4 = (const uint4*)&hb0[(g16 + b) * 512 + n0];
      uint4 v0 = s4[0], v1 = s4[1];
      int sw = (b & 7) << 3;
      *(uint4*)&hbuf[(b << 9) + (n0 ^ sw)]       = v0;
      *(uint4*)&hbuf[(b << 9) + ((n0 + 8) ^ sw)] = v1;
    }
    __syncthreads();

    unsigned long long wsp = (unsigned long long)wfrag;
    const float2* xsrc = (const float2*)&inputs[((size_t)(g16 + col)) << 10];

#define ISSUE(b1) { const int kt_ = 12 + (b1);                                    \
    _Pragma("unroll")                                                             \
    for (int nt_ = 0; nt_ < 4; nt_++)                                             \
      sv[(b1)*4 + nt_].q = ws[(((w << 2) + nt_) * 16 + kt_) * 64 + lane]; }

#define HREAD(kt_) *(const uint4*)&hbuf[(col << 9) + ((((kt_) << 5) + (quad << 3)) ^ swc)]

    for (int t = 0; t < 512; t++){
      asm volatile("" : "+s"(wsp));
      const uint4* ws = (const uint4*)wsp;

      UQ baug; baug.d[0] = 0; baug.d[1] = 0;
      float2 xv = xsrc[t];
      if (quad == 0){
        baug.b[0] = (__bf16)xv.x; baug.b[1] = (__bf16)xv.y; baug.b[2] = (__bf16)1.0f;
      }

      f32x4 acc[4];
      #pragma unroll
      for (int nt = 0; nt < 4; nt++)
        acc[nt] = __builtin_amdgcn_mfma_f32_16x16x32_bf16(uaug[nt].v, baug.v,
                                                          (f32x4){0.f,0.f,0.f,0.f}, 0, 0, 0);

      UQ sv[16];
      ISSUE(0);
      UQ bh[16];
      #pragma unroll
      for (int kt = 0; kt < 16; kt++)
        bh[kt].q = HREAD(kt);

      #pragma unroll
      for (int kt = 0; kt < 8; kt++){
        #pragma unroll
        for (int nt = 0; nt < 4; nt++)
          acc[nt] = __builtin_amdgcn_mfma_f32_16x16x32_bf16(u[kt*4+nt].v, bh[kt].v, acc[nt], 0, 0, 0);
        if (kt == 0) ISSUE(1);
        if (kt == 2) ISSUE(2);
        if (kt == 4) ISSUE(3);
      }
      #pragma unroll
      for (int kt = 8; kt < 12; kt++){
        #pragma unroll
        for (int nt = 0; nt < 4; nt++){
          UQ a; a.q = wlds[(w * 16 + (kt - 8) * 4 + nt) * 64 + lane];
          acc[nt] = __builtin_amdgcn_mfma_f32_16x16x32_bf16(a.v, bh[kt].v, acc[nt], 0, 0, 0);
        }
      }
      #pragma unroll
      for (int kt = 12; kt < 16; kt++){
        #pragma unroll
        for (int nt = 0; nt < 4; nt++)
          acc[nt] = __builtin_amdgcn_mfma_f32_16x16x32_bf16(sv[(kt-12)*4+nt].v, bh[kt].v, acc[nt], 0, 0, 0);
      }

      __syncthreads();   // barrier A

      #pragma unroll
      for (int nt = 0; nt < 4; nt++){
        UQ hw; hw.d[0] = 0; hw.d[1] = 0;
        #pragma unroll
        for (int r = 0; r < 4; r++){
          float z  = acc[nt][r];
          float e  = __expf(2.0f * z);
          float rc = __builtin_amdgcn_rcpf(e + 1.0f);
          float hn = fmaf(0.9f, h[nt*4+r], 0.1f) - 0.2f * rc;
          h[nt*4+r] = hn;
          hw.b[r] = (__bf16)hn;
        }
        *(unsigned long long*)&hbuf[(col << 9) + ((nbase + (nt << 4) + (quad << 2)) ^ swc)] = hw.d[0];
        *(float4*)&hidden[((size_t)(g16 + col) * 512 + t) * 512 + nbase + (nt << 4) + (quad << 2)] =
            (float4){h[nt*4+0], h[nt*4+1], h[nt*4+2], h[nt*4+3]};
      }
      __syncthreads();   // barrier B

      if (((t + 1) & 63) == 0){
        asm volatile("s_waitcnt vmcnt(0)" ::: "memory");
        __syncthreads();
        if (tid == 0){
          __builtin_amdgcn_fence(__ATOMIC_RELEASE, "agent");
          __hip_atomic_store(&progress[m], t + 1, __ATOMIC_RELAXED, __HIP_MEMORY_SCOPE_AGENT);
        }
      }
    }
#undef ISSUE
#undef HREAD
  } else {
    // ========== GEMM role: 64-row tiles, t-chunk-major, upfront staging ======
    const int gid = bid - 16;                 // 0..2047
    const int tchunk = gid >> 8;              // 0..7  (dispatch order == time)
    const int b   = gid & 255;                // batch
    const int t0  = tchunk << 6;
    const int m0  = (b << 9) + t0;            // row base (64 rows)
    const int grp = b >> 4;
    const int ms  = w >> 1;                   // 0..3: 16-row slice
    const int nh  = w & 1;                    // 0..1: 256-col half
    unsigned short* albf = (unsigned short*)smem;      // 64 KB A-tile (64x512 bf16)
    uint4* wq = (uint4*)(smem + 65536);                // 32 KB W-frags per kt

    if (tid == 0)
      while (__hip_atomic_load(&progress[grp], __ATOMIC_RELAXED,
                               __HIP_MEMORY_SCOPE_AGENT) < t0 + 64) {}
    __syncthreads();

    // ---- stage full 64x512 A-tile: 32 pipelined atomic ULL loads per thread
    // swizzle: 16B-slot ^= (r&7) ^ block(byte>>7) — conflict-free writes,
    // consistent read XOR below.
    {
      const int r  = tid >> 3;                // 0..63
      const int c0 = (tid & 7) << 6;          // halfword col base, 0..448
      const unsigned long long* hp =
          (const unsigned long long*)&hidden[(size_t)(m0 + r) * 512 + c0];
      unsigned long long dv[32];
      #pragma unroll
      for (int j = 0; j < 32; j++)
        dv[j] = __hip_atomic_load(hp + j, __ATOMIC_RELAXED, __HIP_MEMORY_SCOPE_AGENT);
      const int sw = (((r & 7) ^ (c0 >> 6)) << 4);   // byte swizzle (bits 4-6)
      #pragma unroll
      for (int g = 0; g < 8; g++){            // 8 halfwords per group -> uint4
        union { unsigned long long d[4]; float f[8]; } cv;
        cv.d[0] = dv[g*4]; cv.d[1] = dv[g*4+1]; cv.d[2] = dv[g*4+2]; cv.d[3] = dv[g*4+3];
        uint4 o;
        o.x = f2bf(cv.f[0]) | ((unsigned)f2bf(cv.f[1]) << 16);
        o.y = f2bf(cv.f[2]) | ((unsigned)f2bf(cv.f[3]) << 16);
        o.z = f2bf(cv.f[4]) | ((unsigned)f2bf(cv.f[5]) << 16);
        o.w = f2bf(cv.f[6]) | ((unsigned)f2bf(cv.f[7]) << 16);
        int byteoff = (r << 10) + ((((c0 + (g << 3)) << 1)) ^ sw);
        *(uint4*)((char*)albf + byteoff) = o;
      }
    }
    __syncthreads();

    f32x4 acc[16];
    #pragma unroll
    for (int nt = 0; nt < 16; nt++) acc[nt] = (f32x4){0.f, 0.f, 0.f, 0.f};

    for (int kt = 0; kt < 16; kt++){
      // stage W-frags for this kt: 32 frags x 64 lanes, 4 per thread
      #pragma unroll
      for (int j = 0; j < 4; j++){
        int idx = (j << 9) + tid;             // 0..2047
        wq[(idx >> 6) * 64 + (idx & 63)] = wofrag[(((idx >> 6) << 4) + kt) * 64 + (idx & 63)];
      }
      __syncthreads();

      bf16x8 af;
      {
        int rl = (ms << 4) + col;
        int byteoff = (rl << 10)
                    + (((kt << 6) + (quad << 4)) ^ ((((rl & 7) ^ (kt >> 1)) << 4)));
        af = *(const bf16x8*)((const char*)albf + byteoff);
      }

      #pragma unroll
      for (int nt = 0; nt < 16; nt++){
        UQ uu; uu.q = wq[((nh << 4) + nt) * 64 + lane];
        acc[nt] = __builtin_amdgcn_mfma_f32_16x16x32_bf16(af, uu.v, acc[nt], 0, 0, 0);
      }
      __syncthreads();
    }

    #pragma unroll
    for (int nt = 0; nt < 16; nt++)
      #pragma unroll
      for (int r = 0; r < 4; r++)
        outp[(size_t)(m0 + (ms << 4) + (quad << 2) + r) * 512
             + (nh << 8) + (nt << 4) + col] = acc[nt][r];
  }
}

extern "C" void kernel_launch(void* const* d_in, const int* in_sizes, int n_in,
                              void* d_out, int out_size, void* d_ws, size_t ws_size,
                              hipStream_t stream){
  const float* inputs  = (const float*)d_in[0];  // (256,512,2)
  const float* initc   = (const float*)d_in[1];  // (256,512)
  const float* W_in    = (const float*)d_in[2];  // (512,2)
  const float* b_in    = (const float*)d_in[3];  // (512)
  const float* W_rec   = (const float*)d_in[4];  // (512,512)
  const float* b_rec   = (const float*)d_in[5];  // (512)
  const float* W_out   = (const float*)d_in[6];  // (512,512)
  const float* W_hi    = (const float*)d_in[7];  // (512,512)

  float* hidden  = (float*)d_out;                 // 256*512*512
  float* outputs = hidden + (size_t)67108864;     // second half

  char* ws = (char*)d_ws;
  uint4*          wrec_f  = (uint4*)ws;                           // 512 KB
  uint4*          wout_f  = (uint4*)(ws + (512 << 10));           // 512 KB
  float*          h0      = (float*)(ws + (1024 << 10));          // 512 KB
  unsigned short* hb0     = (unsigned short*)(ws + (1536 << 10)); // 256 KB
  int*            progress= (int*)(ws + (1792 << 10));            // 64 B

  zero_flags<<<1, 64, 0, stream>>>(progress);
  pack_kernel<<<64, 512, 0, stream>>>(W_rec, wrec_f);
  pack_kernel<<<64, 512, 0, stream>>>(W_out, wout_f);
  h0_kernel<<<256, 512, 0, stream>>>(initc, W_hi, h0, hb0);
  rnn_gemm<<<2064, 512, 0, stream>>>(inputs, W_in, b_in, b_rec, wrec_f, wout_f,
                                     h0, hb0, progress, hidden, outputs);
}